// Round 15
// baseline (56.166 us; speedup 1.0000x reference)
//
#include <hip/hip_runtime.h>
#include <math.h>

#define TPB 512
#define AL_ST 88      // alphaM row stride in shorts (spreads es/ed pad banks)
typedef short bfrag __attribute__((ext_vector_type(8)));   // 8 x bf16
typedef float facc4 __attribute__((ext_vector_type(4)));   // 4 x f32
typedef unsigned int u32;

// ws layout (in shorts)
#define O_INW 0        // 2048   : in_w packed (4 tiles, K=16 padded to 32)
#define O_G0  2048     // 17408  : gat0 W, 2 ksteps x 17 tiles (tile16 = fold)
#define O_G1  19456    // 69632  : gat1 W, 8 ksteps x 17 tiles
#define O_G2  89088    // 69632  : gat2 W
#define O_W1  158720   // 8192   : mlp w1, 2 ksteps x 8 tiles
#define O_W2  166912   // 32768  : mlp w2, 4 ksteps x 16 tiles

// HW packed f32->bf16 (RNE)
__device__ __forceinline__ u32 pk2bf(float lo, float hi) {
    u32 r;
    asm("v_cvt_pk_bf16_f32 %0, %1, %2" : "=v"(r) : "v"(lo), "v"(hi));
    return r;
}
__device__ __forceinline__ short f2bf(float x) {
    return (short)pk2bf(x, 0.f);
}

// swizzled ht index: row-major [16][256] bf16, col bits 3..5 XOR'd with row&7
__device__ __forceinline__ int ht_sw(int row, int col) {
    return row * 256 + (col ^ ((row & 7) << 3));
}

// ============================ weight prep ============================
__device__ __forceinline__ void pack_frag(const float* __restrict__ W, short* __restrict__ out,
                                          int blk, int NCOL, int TSTR) {
    int u = blk * 256 + threadIdx.x;
    int NT = NCOL >> 4;
    int j = u & 7, l = (u >> 3) & 63, q = u >> 9;
    int nt = q % NT, s = q / NT;
    int k = 32 * s + 8 * (l >> 4) + j;
    int c = 16 * nt + (l & 15);
    out[((s * TSTR + nt) * 64 + l) * 8 + j] = f2bf(W[k * NCOL + c]);
}

__device__ __forceinline__ void pack_fold(const float* __restrict__ W,
                                          const float* __restrict__ as_, const float* __restrict__ ad_,
                                          short* __restrict__ out, int blk, int TSTR) {
    int u = blk * 256 + threadIdx.x;
    int j = u & 7, l = (u >> 3) & 63, s = u >> 9;
    int c = l & 15;
    int k = 32 * s + 8 * (l >> 4) + j;
    float v = 0.f;
    if (c < 8) {
        int h = c >> 1;
        const float* a = (c & 1) ? ad_ : as_;
        for (int f = 0; f < 64; ++f) v += W[k * 256 + h * 64 + f] * a[h * 64 + f];
    }
    out[((s * TSTR + 16) * 64 + l) * 8 + j] = f2bf(v);
}

__device__ __forceinline__ void pack_inw(const float* __restrict__ inw, short* __restrict__ out, int blk) {
    int u = blk * 256 + threadIdx.x;
    int j = u & 7, l = (u >> 3) & 63, nt = u >> 9;
    int k = 8 * (l >> 4) + j;
    out[u] = (k < 16) ? f2bf(inw[k * 64 + 16 * nt + (l & 15)]) : (short)0;
}

__global__ void prep_all(const float* __restrict__ g0w, const float* __restrict__ g1w,
                         const float* __restrict__ g2w, const float* __restrict__ mw1,
                         const float* __restrict__ mw2, const float* __restrict__ inw,
                         const float* __restrict__ g0as, const float* __restrict__ g0ad,
                         const float* __restrict__ g1as, const float* __restrict__ g1ad,
                         const float* __restrict__ g2as, const float* __restrict__ g2ad,
                         short* __restrict__ ws) {
    int blk = blockIdx.x;
    if      (blk < 64)  pack_frag(g0w, ws + O_G0, blk,        256, 17);
    else if (blk < 320) pack_frag(g1w, ws + O_G1, blk - 64,   256, 17);
    else if (blk < 576) pack_frag(g2w, ws + O_G2, blk - 320,  256, 17);
    else if (blk < 608) pack_frag(mw1, ws + O_W1, blk - 576,  128, 8);
    else if (blk < 736) pack_frag(mw2, ws + O_W2, blk - 608,  256, 16);
    else if (blk < 744) pack_inw(inw, ws + O_INW, blk - 736);
    else if (blk < 748) pack_fold(g0w, g0as, g0ad, ws + O_G0, blk - 744, 17);
    else if (blk < 764) pack_fold(g1w, g1as, g1ad, ws + O_G1, blk - 748, 17);
    else                pack_fold(g2w, g2as, g2ad, ws + O_G2, blk - 764, 17);
}

// ============================ GAT core (4 graphs, 8 waves) ============================
// wave w owns col-tiles {2w, 2w+1} (head = w>>1).
// s_ht: 4 x [16][256] swizzled; s_xp: 4 x [256][16];
// s_alphaM: [64 rows = h*16+d][AL_ST shorts]: slots gr*16..gr*16+15 = graph gr alpha;
//           pad floats (short offset 64): {es,ed} x 4 graphs for row index n*4+h.
template<int KSTEPS>
__device__ __forceinline__ void gat_core(
    const short* s_ht, const short* __restrict__ Wp,
    short* s_alphaM, short* s_xp,
    facc4 agg[4][2]) {

    const int t = threadIdx.x;
    const int w = t >> 6, lane = t & 63, g = lane >> 4, ci = lane & 15;
    const facc4 fz = {0.f, 0.f, 0.f, 0.f};
    const bfrag zf = {};
    const bfrag* Wf = (const bfrag*)Wp;

    facc4 acc[4][2] = {{fz, fz}, {fz, fz}, {fz, fz}, {fz, fz}};
    facc4 acce = fz;                       // fold: wave w (w<4) -> graph w
#pragma unroll
    for (int s = 0; s < KSTEPS; ++s) {
        int aoff = ht_sw(ci, s * 32 + g * 8);
        bfrag a0 = *(const bfrag*)(s_ht + 0 * 4096 + aoff);
        bfrag a1 = *(const bfrag*)(s_ht + 1 * 4096 + aoff);
        bfrag a2 = *(const bfrag*)(s_ht + 2 * 4096 + aoff);
        bfrag a3 = *(const bfrag*)(s_ht + 3 * 4096 + aoff);
        __builtin_amdgcn_s_setprio(1);
#pragma unroll
        for (int tt = 0; tt < 2; ++tt) {
            bfrag bf = Wf[(s * 17 + 2 * w + tt) * 64 + lane];
            acc[0][tt] = __builtin_amdgcn_mfma_f32_16x16x32_bf16(a0, bf, acc[0][tt], 0, 0, 0);
            acc[1][tt] = __builtin_amdgcn_mfma_f32_16x16x32_bf16(a1, bf, acc[1][tt], 0, 0, 0);
            acc[2][tt] = __builtin_amdgcn_mfma_f32_16x16x32_bf16(a2, bf, acc[2][tt], 0, 0, 0);
            acc[3][tt] = __builtin_amdgcn_mfma_f32_16x16x32_bf16(a3, bf, acc[3][tt], 0, 0, 0);
        }
        if (w < 4) {                       // fold for graph w; A picked from registers
            bfrag afold = a0;              // (w is wave-uniform -> scalar branches)
            if (w == 1) afold = a1;
            else if (w == 2) afold = a2;
            else if (w == 3) afold = a3;
            bfrag bfold = Wf[(s * 17 + 16) * 64 + lane];
            acce = __builtin_amdgcn_mfma_f32_16x16x32_bf16(afold, bfold, acce, 0, 0, 0);
        }
        __builtin_amdgcn_s_setprio(0);
    }

    // stash xp^T for all 4 graphs
#pragma unroll
    for (int gr = 0; gr < 4; ++gr)
#pragma unroll
        for (int tt = 0; tt < 2; ++tt) {
            int col = 32 * w + 16 * tt + ci;
            *(uint2*)(s_xp + gr * 4096 + col * 16 + 4 * g) =
                make_uint2(pk2bf(acc[gr][tt][0], acc[gr][tt][1]),
                           pk2bf(acc[gr][tt][2], acc[gr][tt][3]));
        }
    if (w < 4 && ci < 8) {                 // es/ed for graph w -> alphaM pad floats
        int h = ci >> 1, isD = ci & 1;
#pragma unroll
        for (int r = 0; r < 4; ++r) {
            int idx = (4 * g + r) * 4 + h;                    // node*4 + head
            float* padf = (float*)(s_alphaM + idx * AL_ST + 64);
            padf[w * 2 + isD] = acce[r];
        }
    }
    __syncthreads();                        // B1: ht reads done; xp, es/ed visible

    if (t < 256) {                          // softmax: 4 graphs x 64 tasks, branchless
        int gr = t >> 6, tl = t & 63, d = tl & 15, h = tl >> 4;
        int ii = d >> 2, jj = d & 3;
        const int go = gr * 2;
        float edv = ((const float*)(s_alphaM + (d * 4 + h) * AL_ST + 64))[go + 1];
        bool v1 = (jj > 0), v2 = (jj < 3), v3 = (ii > 0), v4 = (ii < 3);
        int s1 = v1 ? d - 1 : d, s2 = v2 ? d + 1 : d;
        int s3 = v3 ? d - 4 : d, s4 = v4 ? d + 4 : d;
        float e0 = ((const float*)(s_alphaM + (d  * 4 + h) * AL_ST + 64))[go];
        float e1 = ((const float*)(s_alphaM + (s1 * 4 + h) * AL_ST + 64))[go];
        float e2 = ((const float*)(s_alphaM + (s2 * 4 + h) * AL_ST + 64))[go];
        float e3 = ((const float*)(s_alphaM + (s3 * 4 + h) * AL_ST + 64))[go];
        float e4 = ((const float*)(s_alphaM + (s4 * 4 + h) * AL_ST + 64))[go];
        float l0 = e0 + edv; l0 = (l0 > 0.f) ? l0 : 0.2f * l0;
        float l1 = e1 + edv; l1 = (l1 > 0.f) ? l1 : 0.2f * l1; l1 = v1 ? l1 : -1e30f;
        float l2 = e2 + edv; l2 = (l2 > 0.f) ? l2 : 0.2f * l2; l2 = v2 ? l2 : -1e30f;
        float l3 = e3 + edv; l3 = (l3 > 0.f) ? l3 : 0.2f * l3; l3 = v3 ? l3 : -1e30f;
        float l4 = e4 + edv; l4 = (l4 > 0.f) ? l4 : 0.2f * l4; l4 = v4 ? l4 : -1e30f;
        float mx = fmaxf(fmaxf(fmaxf(l0, l1), fmaxf(l2, l3)), l4);
        float w0 = __expf(l0 - mx), w1 = __expf(l1 - mx), w2 = __expf(l2 - mx);
        float w3 = __expf(l3 - mx), w4 = __expf(l4 - mx);
        float inv = 1.f / (w0 + w1 + w2 + w3 + w4);
        short* base = s_alphaM + (h * 16 + d) * AL_ST + gr * 16;
        base[s1] = f2bf(w1 * inv);
        base[s2] = f2bf(w2 * inv);
        base[s3] = f2bf(w3 * inv);
        base[s4] = f2bf(w4 * inv);
        base[d]  = f2bf(w0 * inv);          // self last corrects invalid-slot writes
    }
    __syncthreads();                        // B2: alphaM ready

    // aggregation: two masked K=32 MFMA sets (graphs 0/1 then 2/3)
    const int hrow = w >> 1;
    bfrag arawA = *(const bfrag*)(s_alphaM + (hrow * 16 + ci) * AL_ST + g * 8);
    bfrag arawB = *(const bfrag*)(s_alphaM + (hrow * 16 + ci) * AL_ST + 32 + g * 8);
    bfrag af0 = (g < 2) ? arawA : zf;      // graph0 alpha: slots 0..15 (k 0..15)
    bfrag af1 = (g < 2) ? zf : arawA;      // graph1 alpha: slots 16..31 (k 16..31)
    bfrag af2 = (g < 2) ? arawB : zf;      // graph2: slots 32..47
    bfrag af3 = (g < 2) ? zf : arawB;      // graph3: slots 48..63
    const short* xsrcA = (g < 2) ? (s_xp + 0 * 4096) : (s_xp + 1 * 4096);
    const short* xsrcB = (g < 2) ? (s_xp + 2 * 4096) : (s_xp + 3 * 4096);
    const int xoff = (g & 1) * 8;
#pragma unroll
    for (int tt = 0; tt < 2; ++tt) {
        int col = 32 * w + 16 * tt + ci;
        bfrag xfA = *(const bfrag*)(xsrcA + col * 16 + xoff);
        bfrag xfB = *(const bfrag*)(xsrcB + col * 16 + xoff);
        agg[0][tt] = __builtin_amdgcn_mfma_f32_16x16x32_bf16(af0, xfA, fz, 0, 0, 0);
        agg[1][tt] = __builtin_amdgcn_mfma_f32_16x16x32_bf16(af1, xfA, fz, 0, 0, 0);
        agg[2][tt] = __builtin_amdgcn_mfma_f32_16x16x32_bf16(af2, xfB, fz, 0, 0, 0);
        agg[3][tt] = __builtin_amdgcn_mfma_f32_16x16x32_bf16(af3, xfB, fz, 0, 0, 0);
    }
}

// ============================ fused kernel ============================
__global__ __launch_bounds__(TPB, 4) void gat_fused(
    const float* __restrict__ x,  const float* __restrict__ in_b,
    const short* __restrict__ ws,
    const float* __restrict__ g0_b, const float* __restrict__ g1_b, const float* __restrict__ g2_b,
    const float* __restrict__ b1,   const float* __restrict__ ln1g, const float* __restrict__ ln1b,
    const float* __restrict__ b2,   const float* __restrict__ ln2g, const float* __restrict__ ln2b,
    float* __restrict__ out) {

    __shared__ __align__(16) short s_ht[4 * 16 * 256];     // 32768 B, swizzled
    __shared__ __align__(16) short s_xp[4 * 256 * 16];     // 32768 B
    __shared__ __align__(16) short s_alphaM[64 * AL_ST];   // 11264 B (alpha + es/ed pad)
    // total 76800 B -> 2 blocks/CU, 16 waves/CU

    // tail-phase aliases into s_ht (dead after gat2's GEMM reads)
    float* s_hsum = (float*)s_ht;                          // [4][256] f32
    short* s_gb   = (short*)((char*)s_ht + 4096);          // [4][64] bf16
    short* s_y2b  = (short*)((char*)s_ht + 4608);          // [4][128] bf16
    float* s_part = (float*)((char*)s_ht + 5632);          // [4][16] f32

    const int b = blockIdx.x, t = threadIdx.x;
    const int w = t >> 6, lane = t & 63, g = lane >> 4, ci = lane & 15;
    const facc4 fz = {0.f, 0.f, 0.f, 0.f};
    const bfrag zf = {};

    // zero alphaM slots 0..63 of all 64 rows (pads hold es/ed, rewritten per layer)
    {
        int row = t >> 3, q = t & 7;
        *(uint4*)(s_alphaM + row * AL_ST + q * 8) = make_uint4(0, 0, 0, 0);
    }

    // ---- in-proj via MFMA: wave w -> graph w>>1, tiles {2(w&1), 2(w&1)+1} ----
    {
        const int gi = w >> 1;
        bfrag a0 = {};
        if (g < 2) {
            float xv[8];
#pragma unroll
            for (int j = 0; j < 8; ++j) xv[j] = x[(4 * b + gi) * 256 + (8 * g + j) * 16 + ci];
            u32* ap = (u32*)&a0;
#pragma unroll
            for (int j = 0; j < 4; ++j) ap[j] = pk2bf(xv[2 * j], xv[2 * j + 1]);
        }
        const bfrag* Iw = (const bfrag*)(ws + O_INW);
#pragma unroll
        for (int ntt = 0; ntt < 2; ++ntt) {
            int nt = 2 * (w & 1) + ntt;
            facc4 h = __builtin_amdgcn_mfma_f32_16x16x32_bf16(a0, Iw[nt * 64 + lane], fz, 0, 0, 0);
            float ib = in_b[16 * nt + ci];
#pragma unroll
            for (int r = 0; r < 4; ++r)
                s_ht[gi * 4096 + ht_sw(4 * g + r, 16 * nt + ci)] = f2bf(fmaxf(h[r] + ib, 0.f));
        }
    }
    __syncthreads();

    facc4 agg[4][2];

    // ---- GAT 0 (K=64) ----
    gat_core<2>(s_ht, ws + O_G0, s_alphaM, s_xp, agg);
#pragma unroll
    for (int tt = 0; tt < 2; ++tt) {
        float bb = g0_b[32 * w + 16 * tt + ci];
#pragma unroll
        for (int gr = 0; gr < 4; ++gr)
#pragma unroll
            for (int r = 0; r < 4; ++r)
                s_ht[gr * 4096 + ht_sw(4 * g + r, 32 * w + 16 * tt + ci)] = f2bf(fmaxf(agg[gr][tt][r] + bb, 0.f));
    }
    __syncthreads();

    // ---- GAT 1 (K=256) ----
    gat_core<8>(s_ht, ws + O_G1, s_alphaM, s_xp, agg);
#pragma unroll
    for (int tt = 0; tt < 2; ++tt) {
        float bb = g1_b[32 * w + 16 * tt + ci];
#pragma unroll
        for (int gr = 0; gr < 4; ++gr)
#pragma unroll
            for (int r = 0; r < 4; ++r)
                s_ht[gr * 4096 + ht_sw(4 * g + r, 32 * w + 16 * tt + ci)] = f2bf(fmaxf(agg[gr][tt][r] + bb, 0.f));
    }
    __syncthreads();

    // ---- GAT 2 (K=256) + mean pool over nodes & heads ----
    gat_core<8>(s_ht, ws + O_G2, s_alphaM, s_xp, agg);
    __syncthreads();                        // all xp/alpha reads done; ht region reusable
#pragma unroll
    for (int gr = 0; gr < 4; ++gr)
#pragma unroll
        for (int tt = 0; tt < 2; ++tt) {
            float c = agg[gr][tt][0] + agg[gr][tt][1] + agg[gr][tt][2] + agg[gr][tt][3];
            c += __shfl_xor(c, 16);
            c += __shfl_xor(c, 32);
            if (lane < 16) s_hsum[gr * 256 + 32 * w + 16 * tt + lane] = c;
        }
    __syncthreads();
    if (t < 256) {
        int gr = t >> 6, f = t & 63;
        const float* hs = s_hsum + gr * 256;
        s_gb[gr * 64 + f] = f2bf(g2_b[f] + (hs[f] + hs[64 + f] + hs[128 + f] + hs[192 + f]) * (1.f / 64.f));
    }
    __syncthreads();

    // ---- MLP1: 64->128, wave w -> tile w; A rows 0..3 = graphs; LN; relu ----
    float v1[4];
    {
        const bfrag* W1f = (const bfrag*)(ws + O_W1);
        facc4 m0 = fz;
#pragma unroll
        for (int s = 0; s < 2; ++s) {
            bfrag a = zf;
            if (ci < 4) a = *(const bfrag*)(s_gb + ci * 64 + 32 * s + 8 * g);
            m0 = __builtin_amdgcn_mfma_f32_16x16x32_bf16(a, W1f[(s * 8 + w) * 64 + lane], m0, 0, 0, 0);
        }
        float bb = b1[16 * w + ci];
#pragma unroll
        for (int gr = 0; gr < 4; ++gr) v1[gr] = m0[gr] + bb;   // valid on g==0 lanes
    }
#pragma unroll
    for (int gr = 0; gr < 4; ++gr) {
        float u = (g == 0) ? v1[gr] : 0.f;
        float q = (g == 0) ? v1[gr] * v1[gr] : 0.f;
        u += __shfl_xor(u, 1); u += __shfl_xor(u, 2); u += __shfl_xor(u, 4); u += __shfl_xor(u, 8);
        q += __shfl_xor(q, 1); q += __shfl_xor(q, 2); q += __shfl_xor(q, 4); q += __shfl_xor(q, 8);
        if (lane == 0) { s_part[gr * 16 + w] = u; s_part[gr * 16 + 8 + w] = q; }
    }
    __syncthreads();
#pragma unroll
    for (int gr = 0; gr < 4; ++gr) {
        const float* sp = s_part + gr * 16;
        float sum = sp[0] + sp[1] + sp[2] + sp[3] + sp[4] + sp[5] + sp[6] + sp[7];
        float sq  = sp[8] + sp[9] + sp[10] + sp[11] + sp[12] + sp[13] + sp[14] + sp[15];
        float mn = sum * (1.f / 128.f);
        float var = sq * (1.f / 128.f) - mn * mn;
        float rs = rsqrtf(var + 1e-5f);
        if (g == 0) {
            int col = 16 * w + ci;
            s_y2b[gr * 128 + col] = f2bf(fmaxf((v1[gr] - mn) * rs * ln1g[col] + ln1b[col], 0.f));
        }
    }
    __syncthreads();

    // ---- MLP2: 128->256, wave w -> tiles {2w, 2w+1}; LN; relu; out ----
    float v2[4][2];
    {
        const bfrag* W2f = (const bfrag*)(ws + O_W2);
        facc4 m[2] = {fz, fz};
#pragma unroll
        for (int s = 0; s < 4; ++s) {
            bfrag a = zf;
            if (ci < 4) a = *(const bfrag*)(s_y2b + ci * 128 + 32 * s + 8 * g);
#pragma unroll
            for (int tt = 0; tt < 2; ++tt)
                m[tt] = __builtin_amdgcn_mfma_f32_16x16x32_bf16(a, W2f[(s * 16 + 2 * w + tt) * 64 + lane], m[tt], 0, 0, 0);
        }
#pragma unroll
        for (int tt = 0; tt < 2; ++tt) {
            float bb = b2[32 * w + 16 * tt + ci];
#pragma unroll
            for (int gr = 0; gr < 4; ++gr) v2[gr][tt] = m[tt][gr] + bb;
        }
    }
#pragma unroll
    for (int gr = 0; gr < 4; ++gr) {
        float u = (g == 0) ? v2[gr][0] + v2[gr][1] : 0.f;
        float q = (g == 0) ? v2[gr][0] * v2[gr][0] + v2[gr][1] * v2[gr][1] : 0.f;
        u += __shfl_xor(u, 1); u += __shfl_xor(u, 2); u += __shfl_xor(u, 4); u += __shfl_xor(u, 8);
        q += __shfl_xor(q, 1); q += __shfl_xor(q, 2); q += __shfl_xor(q, 4); q += __shfl_xor(q, 8);
        if (lane == 0) { s_part[gr * 16 + w] = u; s_part[gr * 16 + 8 + w] = q; }
    }
    __syncthreads();
#pragma unroll
    for (int gr = 0; gr < 4; ++gr) {
        const float* sp = s_part + gr * 16;
        float sum = sp[0] + sp[1] + sp[2] + sp[3] + sp[4] + sp[5] + sp[6] + sp[7];
        float sq  = sp[8] + sp[9] + sp[10] + sp[11] + sp[12] + sp[13] + sp[14] + sp[15];
        float mn = sum * (1.f / 256.f);
        float var = sq * (1.f / 256.f) - mn * mn;
        float rs = rsqrtf(var + 1e-5f);
        if (g == 0) {
#pragma unroll
            for (int tt = 0; tt < 2; ++tt) {
                int col = 32 * w + 16 * tt + ci;
                out[(4 * b + gr) * 256 + col] = fmaxf((v2[gr][tt] - mn) * rs * ln2g[col] + ln2b[col], 0.f);
            }
        }
    }
}

extern "C" void kernel_launch(void* const* d_in, const int* in_sizes, int n_in,
                              void* d_out, int out_size, void* d_ws, size_t ws_size,
                              hipStream_t stream) {
    const float* x    = (const float*)d_in[0];
    const float* in_w = (const float*)d_in[1];
    const float* in_b = (const float*)d_in[2];
    const float* g0w  = (const float*)d_in[3];
    const float* g0as = (const float*)d_in[4];
    const float* g0ad = (const float*)d_in[5];
    const float* g0b  = (const float*)d_in[6];
    const float* g1w  = (const float*)d_in[7];
    const float* g1as = (const float*)d_in[8];
    const float* g1ad = (const float*)d_in[9];
    const float* g1b  = (const float*)d_in[10];
    const float* g2w  = (const float*)d_in[11];
    const float* g2as = (const float*)d_in[12];
    const float* g2ad = (const float*)d_in[13];
    const float* g2b  = (const float*)d_in[14];
    const float* w1   = (const float*)d_in[15];
    const float* b1   = (const float*)d_in[16];
    const float* ln1g = (const float*)d_in[17];
    const float* ln1b = (const float*)d_in[18];
    const float* w2   = (const float*)d_in[19];
    const float* b2   = (const float*)d_in[20];
    const float* ln2g = (const float*)d_in[21];
    const float* ln2b = (const float*)d_in[22];

    const int B = in_sizes[0] / 256;
    short* wsb = (short*)d_ws;

    prep_all<<<780, 256, 0, stream>>>(g0w, g1w, g2w, w1, w2, in_w,
                                      g0as, g0ad, g1as, g1ad, g2as, g2ad, wsb);

    gat_fused<<<B / 4, TPB, 0, stream>>>(
        x, in_b, wsb,
        g0b, g1b, g2b,
        b1, ln1g, ln1b,
        b2, ln2g, ln2b,
        (float*)d_out);
}

// Round 16
// 54.435 us; speedup vs baseline: 1.0318x; 1.0318x over previous
//
#include <hip/hip_runtime.h>
#include <math.h>

#define TPB 512
#define AL_ST 88      // alphaM row stride in shorts (spreads es/ed pad banks)
typedef short bfrag __attribute__((ext_vector_type(8)));   // 8 x bf16
typedef float facc4 __attribute__((ext_vector_type(4)));   // 4 x f32
typedef unsigned int u32;

// ws layout (in shorts)
#define O_INW 0        // 2048   : in_w packed (4 tiles, K=16 padded to 32)
#define O_G0  2048     // 17408  : gat0 W, 2 ksteps x 17 tiles (tile16 = fold)
#define O_G1  19456    // 69632  : gat1 W, 8 ksteps x 17 tiles
#define O_G2  89088    // 69632  : gat2 W
#define O_W1  158720   // 8192   : mlp w1, 2 ksteps x 8 tiles
#define O_W2  166912   // 32768  : mlp w2, 4 ksteps x 16 tiles

// HW packed f32->bf16 (RNE)
__device__ __forceinline__ u32 pk2bf(float lo, float hi) {
    u32 r;
    asm("v_cvt_pk_bf16_f32 %0, %1, %2" : "=v"(r) : "v"(lo), "v"(hi));
    return r;
}
__device__ __forceinline__ short f2bf(float x) {
    return (short)pk2bf(x, 0.f);
}

// swizzled ht index: row-major [16][256] bf16, col bits 3..5 XOR'd with row&7
__device__ __forceinline__ int ht_sw(int row, int col) {
    return row * 256 + (col ^ ((row & 7) << 3));
}

// ============================ weight prep ============================
__device__ __forceinline__ void pack_frag(const float* __restrict__ W, short* __restrict__ out,
                                          int blk, int NCOL, int TSTR) {
    int u = blk * 256 + threadIdx.x;
    int NT = NCOL >> 4;
    int j = u & 7, l = (u >> 3) & 63, q = u >> 9;
    int nt = q % NT, s = q / NT;
    int k = 32 * s + 8 * (l >> 4) + j;
    int c = 16 * nt + (l & 15);
    out[((s * TSTR + nt) * 64 + l) * 8 + j] = f2bf(W[k * NCOL + c]);
}

__device__ __forceinline__ void pack_fold(const float* __restrict__ W,
                                          const float* __restrict__ as_, const float* __restrict__ ad_,
                                          short* __restrict__ out, int blk, int TSTR) {
    int u = blk * 256 + threadIdx.x;
    int j = u & 7, l = (u >> 3) & 63, s = u >> 9;
    int c = l & 15;
    int k = 32 * s + 8 * (l >> 4) + j;
    float v = 0.f;
    if (c < 8) {
        int h = c >> 1;
        const float* a = (c & 1) ? ad_ : as_;
        const float4* wv = (const float4*)(W + k * 256 + h * 64);
        const float4* av = (const float4*)(a + h * 64);
#pragma unroll
        for (int f4 = 0; f4 < 16; ++f4) {
            float4 wq = wv[f4], aq = av[f4];
            v += wq.x * aq.x + wq.y * aq.y + wq.z * aq.z + wq.w * aq.w;
        }
    }
    out[((s * TSTR + 16) * 64 + l) * 8 + j] = f2bf(v);
}

__device__ __forceinline__ void pack_inw(const float* __restrict__ inw, short* __restrict__ out, int blk) {
    int u = blk * 256 + threadIdx.x;
    int j = u & 7, l = (u >> 3) & 63, nt = u >> 9;
    int k = 8 * (l >> 4) + j;
    out[u] = (k < 16) ? f2bf(inw[k * 64 + 16 * nt + (l & 15)]) : (short)0;
}

__global__ void prep_all(const float* __restrict__ g0w, const float* __restrict__ g1w,
                         const float* __restrict__ g2w, const float* __restrict__ mw1,
                         const float* __restrict__ mw2, const float* __restrict__ inw,
                         const float* __restrict__ g0as, const float* __restrict__ g0ad,
                         const float* __restrict__ g1as, const float* __restrict__ g1ad,
                         const float* __restrict__ g2as, const float* __restrict__ g2ad,
                         short* __restrict__ ws) {
    int blk = blockIdx.x;
    if      (blk < 64)  pack_frag(g0w, ws + O_G0, blk,        256, 17);
    else if (blk < 320) pack_frag(g1w, ws + O_G1, blk - 64,   256, 17);
    else if (blk < 576) pack_frag(g2w, ws + O_G2, blk - 320,  256, 17);
    else if (blk < 608) pack_frag(mw1, ws + O_W1, blk - 576,  128, 8);
    else if (blk < 736) pack_frag(mw2, ws + O_W2, blk - 608,  256, 16);
    else if (blk < 744) pack_inw(inw, ws + O_INW, blk - 736);
    else if (blk < 748) pack_fold(g0w, g0as, g0ad, ws + O_G0, blk - 744, 17);
    else if (blk < 764) pack_fold(g1w, g1as, g1ad, ws + O_G1, blk - 748, 17);
    else                pack_fold(g2w, g2as, g2ad, ws + O_G2, blk - 764, 17);
}

// ============================ GAT core (4 graphs, 8 waves) ============================
// wave w owns col-tiles {2w, 2w+1} (head = w>>1).
// s_ht: 4 x [16][256] swizzled; s_xp: 4 x [256][16];
// s_alphaM: [64 rows = h*16+d][AL_ST shorts]: slots gr*16..gr*16+15 = graph gr alpha;
//           pad floats (short offset 64): {es,ed} x 4 graphs for row index n*4+h.
template<int KSTEPS>
__device__ __forceinline__ void gat_core(
    const short* s_ht, const short* __restrict__ Wp,
    short* s_alphaM, short* s_xp,
    facc4 agg[4][2]) {

    const int t = threadIdx.x;
    const int w = t >> 6, lane = t & 63, g = lane >> 4, ci = lane & 15;
    const facc4 fz = {0.f, 0.f, 0.f, 0.f};
    const bfrag zf = {};
    const bfrag* Wf = (const bfrag*)Wp;

    facc4 acc[4][2] = {{fz, fz}, {fz, fz}, {fz, fz}, {fz, fz}};
    facc4 acce = fz;                       // fold: wave w (w<4) -> graph w
#pragma unroll
    for (int s = 0; s < KSTEPS; ++s) {
        int aoff = ht_sw(ci, s * 32 + g * 8);
        bfrag a0 = *(const bfrag*)(s_ht + 0 * 4096 + aoff);
        bfrag a1 = *(const bfrag*)(s_ht + 1 * 4096 + aoff);
        bfrag a2 = *(const bfrag*)(s_ht + 2 * 4096 + aoff);
        bfrag a3 = *(const bfrag*)(s_ht + 3 * 4096 + aoff);
#pragma unroll
        for (int tt = 0; tt < 2; ++tt) {
            bfrag bf = Wf[(s * 17 + 2 * w + tt) * 64 + lane];
            acc[0][tt] = __builtin_amdgcn_mfma_f32_16x16x32_bf16(a0, bf, acc[0][tt], 0, 0, 0);
            acc[1][tt] = __builtin_amdgcn_mfma_f32_16x16x32_bf16(a1, bf, acc[1][tt], 0, 0, 0);
            acc[2][tt] = __builtin_amdgcn_mfma_f32_16x16x32_bf16(a2, bf, acc[2][tt], 0, 0, 0);
            acc[3][tt] = __builtin_amdgcn_mfma_f32_16x16x32_bf16(a3, bf, acc[3][tt], 0, 0, 0);
        }
        if (w < 4) {                       // fold for graph w (re-read A from LDS: uniform base)
            bfrag afold = *(const bfrag*)(s_ht + w * 4096 + aoff);
            bfrag bfold = Wf[(s * 17 + 16) * 64 + lane];
            acce = __builtin_amdgcn_mfma_f32_16x16x32_bf16(afold, bfold, acce, 0, 0, 0);
        }
    }

    // stash xp^T for all 4 graphs
#pragma unroll
    for (int gr = 0; gr < 4; ++gr)
#pragma unroll
        for (int tt = 0; tt < 2; ++tt) {
            int col = 32 * w + 16 * tt + ci;
            *(uint2*)(s_xp + gr * 4096 + col * 16 + 4 * g) =
                make_uint2(pk2bf(acc[gr][tt][0], acc[gr][tt][1]),
                           pk2bf(acc[gr][tt][2], acc[gr][tt][3]));
        }
    if (w < 4 && ci < 8) {                 // es/ed for graph w -> alphaM pad floats
        int h = ci >> 1, isD = ci & 1;
#pragma unroll
        for (int r = 0; r < 4; ++r) {
            int idx = (4 * g + r) * 4 + h;                    // node*4 + head
            float* padf = (float*)(s_alphaM + idx * AL_ST + 64);
            padf[w * 2 + isD] = acce[r];
        }
    }
    __syncthreads();                        // B1: ht reads done; xp, es/ed visible

    if (t < 256) {                          // softmax: 4 graphs x 64 tasks, branchless
        int gr = t >> 6, tl = t & 63, d = tl & 15, h = tl >> 4;
        int ii = d >> 2, jj = d & 3;
        const int go = gr * 2;
        float edv = ((const float*)(s_alphaM + (d * 4 + h) * AL_ST + 64))[go + 1];
        bool v1 = (jj > 0), v2 = (jj < 3), v3 = (ii > 0), v4 = (ii < 3);
        int s1 = v1 ? d - 1 : d, s2 = v2 ? d + 1 : d;
        int s3 = v3 ? d - 4 : d, s4 = v4 ? d + 4 : d;
        float e0 = ((const float*)(s_alphaM + (d  * 4 + h) * AL_ST + 64))[go];
        float e1 = ((const float*)(s_alphaM + (s1 * 4 + h) * AL_ST + 64))[go];
        float e2 = ((const float*)(s_alphaM + (s2 * 4 + h) * AL_ST + 64))[go];
        float e3 = ((const float*)(s_alphaM + (s3 * 4 + h) * AL_ST + 64))[go];
        float e4 = ((const float*)(s_alphaM + (s4 * 4 + h) * AL_ST + 64))[go];
        float l0 = e0 + edv; l0 = (l0 > 0.f) ? l0 : 0.2f * l0;
        float l1 = e1 + edv; l1 = (l1 > 0.f) ? l1 : 0.2f * l1; l1 = v1 ? l1 : -1e30f;
        float l2 = e2 + edv; l2 = (l2 > 0.f) ? l2 : 0.2f * l2; l2 = v2 ? l2 : -1e30f;
        float l3 = e3 + edv; l3 = (l3 > 0.f) ? l3 : 0.2f * l3; l3 = v3 ? l3 : -1e30f;
        float l4 = e4 + edv; l4 = (l4 > 0.f) ? l4 : 0.2f * l4; l4 = v4 ? l4 : -1e30f;
        float mx = fmaxf(fmaxf(fmaxf(l0, l1), fmaxf(l2, l3)), l4);
        float w0 = __expf(l0 - mx), w1 = __expf(l1 - mx), w2 = __expf(l2 - mx);
        float w3 = __expf(l3 - mx), w4 = __expf(l4 - mx);
        float inv = 1.f / (w0 + w1 + w2 + w3 + w4);
        short* base = s_alphaM + (h * 16 + d) * AL_ST + gr * 16;
        base[s1] = f2bf(w1 * inv);
        base[s2] = f2bf(w2 * inv);
        base[s3] = f2bf(w3 * inv);
        base[s4] = f2bf(w4 * inv);
        base[d]  = f2bf(w0 * inv);          // self last corrects invalid-slot writes
    }
    __syncthreads();                        // B2: alphaM ready

    // aggregation: two masked K=32 MFMA sets (graphs 0/1 then 2/3)
    const int hrow = w >> 1;
    bfrag arawA = *(const bfrag*)(s_alphaM + (hrow * 16 + ci) * AL_ST + g * 8);
    bfrag arawB = *(const bfrag*)(s_alphaM + (hrow * 16 + ci) * AL_ST + 32 + g * 8);
    bfrag af0 = (g < 2) ? arawA : zf;      // graph0 alpha: slots 0..15 (k 0..15)
    bfrag af1 = (g < 2) ? zf : arawA;      // graph1 alpha: slots 16..31 (k 16..31)
    bfrag af2 = (g < 2) ? arawB : zf;      // graph2: slots 32..47
    bfrag af3 = (g < 2) ? zf : arawB;      // graph3: slots 48..63
    const short* xsrcA = (g < 2) ? (s_xp + 0 * 4096) : (s_xp + 1 * 4096);
    const short* xsrcB = (g < 2) ? (s_xp + 2 * 4096) : (s_xp + 3 * 4096);
    const int xoff = (g & 1) * 8;
#pragma unroll
    for (int tt = 0; tt < 2; ++tt) {
        int col = 32 * w + 16 * tt + ci;
        bfrag xfA = *(const bfrag*)(xsrcA + col * 16 + xoff);
        bfrag xfB = *(const bfrag*)(xsrcB + col * 16 + xoff);
        agg[0][tt] = __builtin_amdgcn_mfma_f32_16x16x32_bf16(af0, xfA, fz, 0, 0, 0);
        agg[1][tt] = __builtin_amdgcn_mfma_f32_16x16x32_bf16(af1, xfA, fz, 0, 0, 0);
        agg[2][tt] = __builtin_amdgcn_mfma_f32_16x16x32_bf16(af2, xfB, fz, 0, 0, 0);
        agg[3][tt] = __builtin_amdgcn_mfma_f32_16x16x32_bf16(af3, xfB, fz, 0, 0, 0);
    }
}

// ============================ fused kernel ============================
__global__ __launch_bounds__(TPB, 4) void gat_fused(
    const float* __restrict__ x,  const float* __restrict__ in_b,
    const short* __restrict__ ws,
    const float* __restrict__ g0_b, const float* __restrict__ g1_b, const float* __restrict__ g2_b,
    const float* __restrict__ b1,   const float* __restrict__ ln1g, const float* __restrict__ ln1b,
    const float* __restrict__ b2,   const float* __restrict__ ln2g, const float* __restrict__ ln2b,
    float* __restrict__ out) {

    __shared__ __align__(16) short s_ht[4 * 16 * 256];     // 32768 B, swizzled
    __shared__ __align__(16) short s_xp[4 * 256 * 16];     // 32768 B
    __shared__ __align__(16) short s_alphaM[64 * AL_ST];   // 11264 B (alpha + es/ed pad)
    // total 76800 B -> 2 blocks/CU, 16 waves/CU

    // tail-phase aliases into s_ht (dead after gat2's GEMM reads)
    float* s_hsum = (float*)s_ht;                          // [4][256] f32
    short* s_gb   = (short*)((char*)s_ht + 4096);          // [4][64] bf16
    short* s_y2b  = (short*)((char*)s_ht + 4608);          // [4][128] bf16
    float* s_part = (float*)((char*)s_ht + 5632);          // [4][16] f32

    const int b = blockIdx.x, t = threadIdx.x;
    const int w = t >> 6, lane = t & 63, g = lane >> 4, ci = lane & 15;
    const facc4 fz = {0.f, 0.f, 0.f, 0.f};
    const bfrag zf = {};

    // zero alphaM slots 0..63 of all 64 rows (pads hold es/ed, rewritten per layer)
    {
        int row = t >> 3, q = t & 7;
        *(uint4*)(s_alphaM + row * AL_ST + q * 8) = make_uint4(0, 0, 0, 0);
    }

    // ---- in-proj via MFMA: wave w -> graph w>>1, tiles {2(w&1), 2(w&1)+1} ----
    {
        const int gi = w >> 1;
        bfrag a0 = {};
        if (g < 2) {
            float xv[8];
#pragma unroll
            for (int j = 0; j < 8; ++j) xv[j] = x[(4 * b + gi) * 256 + (8 * g + j) * 16 + ci];
            u32* ap = (u32*)&a0;
#pragma unroll
            for (int j = 0; j < 4; ++j) ap[j] = pk2bf(xv[2 * j], xv[2 * j + 1]);
        }
        const bfrag* Iw = (const bfrag*)(ws + O_INW);
#pragma unroll
        for (int ntt = 0; ntt < 2; ++ntt) {
            int nt = 2 * (w & 1) + ntt;
            facc4 h = __builtin_amdgcn_mfma_f32_16x16x32_bf16(a0, Iw[nt * 64 + lane], fz, 0, 0, 0);
            float ib = in_b[16 * nt + ci];
#pragma unroll
            for (int r = 0; r < 4; ++r)
                s_ht[gi * 4096 + ht_sw(4 * g + r, 16 * nt + ci)] = f2bf(fmaxf(h[r] + ib, 0.f));
        }
    }
    __syncthreads();

    facc4 agg[4][2];

    // ---- GAT 0 (K=64) ----
    gat_core<2>(s_ht, ws + O_G0, s_alphaM, s_xp, agg);
#pragma unroll
    for (int tt = 0; tt < 2; ++tt) {
        float bb = g0_b[32 * w + 16 * tt + ci];
#pragma unroll
        for (int gr = 0; gr < 4; ++gr)
#pragma unroll
            for (int r = 0; r < 4; ++r)
                s_ht[gr * 4096 + ht_sw(4 * g + r, 32 * w + 16 * tt + ci)] = f2bf(fmaxf(agg[gr][tt][r] + bb, 0.f));
    }
    __syncthreads();

    // ---- GAT 1 (K=256) ----
    gat_core<8>(s_ht, ws + O_G1, s_alphaM, s_xp, agg);
#pragma unroll
    for (int tt = 0; tt < 2; ++tt) {
        float bb = g1_b[32 * w + 16 * tt + ci];
#pragma unroll
        for (int gr = 0; gr < 4; ++gr)
#pragma unroll
            for (int r = 0; r < 4; ++r)
                s_ht[gr * 4096 + ht_sw(4 * g + r, 32 * w + 16 * tt + ci)] = f2bf(fmaxf(agg[gr][tt][r] + bb, 0.f));
    }
    __syncthreads();

    // ---- GAT 2 (K=256) + mean pool over nodes & heads ----
    gat_core<8>(s_ht, ws + O_G2, s_alphaM, s_xp, agg);
    __syncthreads();                        // all xp/alpha reads done; ht region reusable
#pragma unroll
    for (int gr = 0; gr < 4; ++gr)
#pragma unroll
        for (int tt = 0; tt < 2; ++tt) {
            float c = agg[gr][tt][0] + agg[gr][tt][1] + agg[gr][tt][2] + agg[gr][tt][3];
            c += __shfl_xor(c, 16);
            c += __shfl_xor(c, 32);
            if (lane < 16) s_hsum[gr * 256 + 32 * w + 16 * tt + lane] = c;
        }
    __syncthreads();
    if (t < 256) {
        int gr = t >> 6, f = t & 63;
        const float* hs = s_hsum + gr * 256;
        s_gb[gr * 64 + f] = f2bf(g2_b[f] + (hs[f] + hs[64 + f] + hs[128 + f] + hs[192 + f]) * (1.f / 64.f));
    }
    __syncthreads();

    // ---- MLP1: 64->128, wave w -> tile w; A rows 0..3 = graphs; LN; relu ----
    float v1[4];
    {
        const bfrag* W1f = (const bfrag*)(ws + O_W1);
        facc4 m0 = fz;
#pragma unroll
        for (int s = 0; s < 2; ++s) {
            bfrag a = zf;
            if (ci < 4) a = *(const bfrag*)(s_gb + ci * 64 + 32 * s + 8 * g);
            m0 = __builtin_amdgcn_mfma_f32_16x16x32_bf16(a, W1f[(s * 8 + w) * 64 + lane], m0, 0, 0, 0);
        }
        float bb = b1[16 * w + ci];
#pragma unroll
        for (int gr = 0; gr < 4; ++gr) v1[gr] = m0[gr] + bb;   // valid on g==0 lanes
    }
#pragma unroll
    for (int gr = 0; gr < 4; ++gr) {
        float u = (g == 0) ? v1[gr] : 0.f;
        float q = (g == 0) ? v1[gr] * v1[gr] : 0.f;
        u += __shfl_xor(u, 1); u += __shfl_xor(u, 2); u += __shfl_xor(u, 4); u += __shfl_xor(u, 8);
        q += __shfl_xor(q, 1); q += __shfl_xor(q, 2); q += __shfl_xor(q, 4); q += __shfl_xor(q, 8);
        if (lane == 0) { s_part[gr * 16 + w] = u; s_part[gr * 16 + 8 + w] = q; }
    }
    __syncthreads();
#pragma unroll
    for (int gr = 0; gr < 4; ++gr) {
        const float* sp = s_part + gr * 16;
        float sum = sp[0] + sp[1] + sp[2] + sp[3] + sp[4] + sp[5] + sp[6] + sp[7];
        float sq  = sp[8] + sp[9] + sp[10] + sp[11] + sp[12] + sp[13] + sp[14] + sp[15];
        float mn = sum * (1.f / 128.f);
        float var = sq * (1.f / 128.f) - mn * mn;
        float rs = rsqrtf(var + 1e-5f);
        if (g == 0) {
            int col = 16 * w + ci;
            s_y2b[gr * 128 + col] = f2bf(fmaxf((v1[gr] - mn) * rs * ln1g[col] + ln1b[col], 0.f));
        }
    }
    __syncthreads();

    // ---- MLP2: 128->256, wave w -> tiles {2w, 2w+1}; LN; relu; out ----
    float v2[4][2];
    {
        const bfrag* W2f = (const bfrag*)(ws + O_W2);
        facc4 m[2] = {fz, fz};
#pragma unroll
        for (int s = 0; s < 4; ++s) {
            bfrag a = zf;
            if (ci < 4) a = *(const bfrag*)(s_y2b + ci * 128 + 32 * s + 8 * g);
#pragma unroll
            for (int tt = 0; tt < 2; ++tt)
                m[tt] = __builtin_amdgcn_mfma_f32_16x16x32_bf16(a, W2f[(s * 16 + 2 * w + tt) * 64 + lane], m[tt], 0, 0, 0);
        }
#pragma unroll
        for (int tt = 0; tt < 2; ++tt) {
            float bb = b2[32 * w + 16 * tt + ci];
#pragma unroll
            for (int gr = 0; gr < 4; ++gr) v2[gr][tt] = m[tt][gr] + bb;
        }
    }
#pragma unroll
    for (int gr = 0; gr < 4; ++gr) {
        float u = (g == 0) ? v2[gr][0] + v2[gr][1] : 0.f;
        float q = (g == 0) ? v2[gr][0] * v2[gr][0] + v2[gr][1] * v2[gr][1] : 0.f;
        u += __shfl_xor(u, 1); u += __shfl_xor(u, 2); u += __shfl_xor(u, 4); u += __shfl_xor(u, 8);
        q += __shfl_xor(q, 1); q += __shfl_xor(q, 2); q += __shfl_xor(q, 4); q += __shfl_xor(q, 8);
        if (lane == 0) { s_part[gr * 16 + w] = u; s_part[gr * 16 + 8 + w] = q; }
    }
    __syncthreads();
#pragma unroll
    for (int gr = 0; gr < 4; ++gr) {
        const float* sp = s_part + gr * 16;
        float sum = sp[0] + sp[1] + sp[2] + sp[3] + sp[4] + sp[5] + sp[6] + sp[7];
        float sq  = sp[8] + sp[9] + sp[10] + sp[11] + sp[12] + sp[13] + sp[14] + sp[15];
        float mn = sum * (1.f / 256.f);
        float var = sq * (1.f / 256.f) - mn * mn;
        float rs = rsqrtf(var + 1e-5f);
        if (g == 0) {
#pragma unroll
            for (int tt = 0; tt < 2; ++tt) {
                int col = 32 * w + 16 * tt + ci;
                out[(4 * b + gr) * 256 + col] = fmaxf((v2[gr][tt] - mn) * rs * ln2g[col] + ln2b[col], 0.f);
            }
        }
    }
}

extern "C" void kernel_launch(void* const* d_in, const int* in_sizes, int n_in,
                              void* d_out, int out_size, void* d_ws, size_t ws_size,
                              hipStream_t stream) {
    const float* x    = (const float*)d_in[0];
    const float* in_w = (const float*)d_in[1];
    const float* in_b = (const float*)d_in[2];
    const float* g0w  = (const float*)d_in[3];
    const float* g0as = (const float*)d_in[4];
    const float* g0ad = (const float*)d_in[5];
    const float* g0b  = (const float*)d_in[6];
    const float* g1w  = (const float*)d_in[7];
    const float* g1as = (const float*)d_in[8];
    const float* g1ad = (const float*)d_in[9];
    const float* g1b  = (const float*)d_in[10];
    const float* g2w  = (const float*)d_in[11];
    const float* g2as = (const float*)d_in[12];
    const float* g2ad = (const float*)d_in[13];
    const float* g2b  = (const float*)d_in[14];
    const float* w1   = (const float*)d_in[15];
    const float* b1   = (const float*)d_in[16];
    const float* ln1g = (const float*)d_in[17];
    const float* ln1b = (const float*)d_in[18];
    const float* w2   = (const float*)d_in[19];
    const float* b2   = (const float*)d_in[20];
    const float* ln2g = (const float*)d_in[21];
    const float* ln2b = (const float*)d_in[22];

    const int B = in_sizes[0] / 256;
    short* wsb = (short*)d_ws;

    prep_all<<<780, 256, 0, stream>>>(g0w, g1w, g2w, w1, w2, in_w,
                                      g0as, g0ad, g1as, g1ad, g2as, g2ad, wsb);

    gat_fused<<<B / 4, TPB, 0, stream>>>(
        x, in_b, wsb,
        g0b, g1b, g2b,
        b1, ln1g, ln1b,
        b2, ln2g, ln2b,
        (float*)d_out);
}